// Round 8
// baseline (141.497 us; speedup 1.0000x reference)
//
#include <hip/hip_runtime.h>
#include <math.h>

// Problem constants (fixed by setup_inputs)
constexpr int Bc  = 32768;
constexpr int NAc = 60;

constexpr int WPB  = 4;            // waves per block (1 b per wave)
constexpr int NBLK = Bc / WPB;     // 8192 blocks
constexpr int ROWF = NAc * 9;      // 540 floats of gt_R per b
constexpr int WPAD = 544;          // padded per-wave LDS row (16B-aligned)

// cos(1.0 rad): mask (gt_bias < 1) <=> clip(0.5*(tr-1)) > cos(1)
#define COS_ONE 0.5403023058681398f

// ---------------------------------------------------------------------------
// Fully fused, wave-autonomous: each wave owns one batch element b.
//   - gt_R row-block staged WAVE-PRIVATELY (coalesced float4), so the single
//     barrier only syncs equal-length sibling waves.
//   - rotmat computed once per (b,a), reused for l2 AND ang_err.
//   - true_R = gt_R[b,29] read from the staged LDS tile.
//   - per-wave partials written straight to global: no second barrier.
// ---------------------------------------------------------------------------
__global__ __launch_bounds__(256) void mtl_all(
    const float* __restrict__ wts,      // (B, NA)
    const int*   __restrict__ label,    // (B,)
    const float* __restrict__ y,        // (B, 4, NA)
    const float* __restrict__ gt_R,     // (B, NA, 9)
    const float* __restrict__ anchors,  // (NA, 9)
    float*       __restrict__ out,      // [.., ang_err at 4+b]
    float*       __restrict__ l2p,      // (Bc,)
    float*       __restrict__ lpp,      // (Bc,)
    float*       __restrict__ crp)      // (Bc,)
{
    __shared__ __align__(16) float sg[WPB * WPAD];   // 8704 B
    const int tid  = threadIdx.x;
    const int lane = tid & 63;
    const int wave = tid >> 6;
    const int b    = blockIdx.x * WPB + wave;

    // ---- wave-private staging: 135 float4 over 64 lanes, coalesced ----
    float4*       sgw4 = (float4*)(sg + wave * WPAD);
    const float4* gb4  = (const float4*)(gt_R + (size_t)b * ROWF);   // 16B-aligned (2160B rows)
    sgw4[lane]      = gb4[lane];
    sgw4[lane + 64] = gb4[lane + 64];
    if (lane < 7) sgw4[lane + 128] = gb4[lane + 128];

    // ---- independent register loads (issued alongside staging) ----
    const int a = lane;
    int lab = label[b];
    float w = -INFINITY;
    float qw = 0, qx = 0, qy = 0, qz = 0;
    float A0=0,A1=0,A2=0,A3=0,A4=0,A5=0,A6=0,A7=0,A8=0;
    if (a < NAc) {
        w = wts[(size_t)b * NAc + a];
        const float* yb = y + (size_t)b * (4 * NAc) + a;
        qw = yb[0 * NAc];
        qx = yb[1 * NAc];
        qy = yb[2 * NAc];
        qz = yb[3 * NAc];
        const float* Ar = anchors + a * 9;       // speculative, L2-hot (2 KB)
        A0 = Ar[0]; A1 = Ar[1]; A2 = Ar[2];
        A3 = Ar[3]; A4 = Ar[4]; A5 = Ar[5];
        A6 = Ar[6]; A7 = Ar[7]; A8 = Ar[8];
    }

    // ---- rotmat (serves both l2 and ang_err) ----
    float n   = sqrtf(qw*qw + qx*qx + qy*qy + qz*qz);
    float inv = 1.0f / fmaxf(n, 1e-8f);
    float pw = qw*inv, px = qx*inv, py = qy*inv, pz = qz*inv;
    float R00 = 1.0f - 2.0f*(py*py + pz*pz);
    float R01 = 2.0f*(px*py - pz*pw);
    float R02 = 2.0f*(px*pz + py*pw);
    float R10 = 2.0f*(px*py + pz*pw);
    float R11 = 1.0f - 2.0f*(px*px + pz*pz);
    float R12 = 2.0f*(py*pz - px*pw);
    float R20 = 2.0f*(px*pz - py*pw);
    float R21 = 2.0f*(py*pz + px*pw);
    float R22 = 1.0f - 2.0f*(px*px + py*py);

    __syncthreads();   // siblings have equal-length staging: minimal skew

    // ---- masked Frobenius term for pair (b, a) ----
    float acc = 0.0f;
    if (a < NAc) {
        const float* g = sg + wave * WPAD + a * 9;   // 2-way bank alias: free
        float g0 = g[0], g1 = g[1], g2 = g[2];
        float g3 = g[3], g4 = g[4], g5 = g[5];
        float g6 = g[6], g7 = g[7], g8 = g[8];
        float xb = 0.5f * (g0 + g4 + g8 - 1.0f);
        if (xb > COS_ONE) {
            float d0 = g0-R00, d1 = g1-R01, d2 = g2-R02;
            float d3 = g3-R10, d4 = g4-R11, d5 = g5-R12;
            float d6 = g6-R20, d7 = g7-R21, d8 = g8-R22;
            acc = d0*d0 + d1*d1 + d2*d2
                + d3*d3 + d4*d4 + d5*d5
                + d6*d6 + d7*d7 + d8*d8;
        }
    }

    // ---- softmax / argmax (first-index tie-break) ----
    float mv = w;
    int   mi = lane;
    for (int off = 32; off; off >>= 1) {
        float ov = __shfl_xor(mv, off, 64);
        int   oi = __shfl_xor(mi, off, 64);
        if (ov > mv || (ov == mv && oi < mi)) { mv = ov; mi = oi; }
    }
    float e  = (a < NAc) ? expf(w - mv) : 0.0f;
    float se = e;
    for (int off = 32; off; off >>= 1) se += __shfl_xor(se, off, 64);
    float lse  = mv + logf(se);
    float wlab = __shfl(w, lab, 64);

    // ---- ang_err: winning lane already holds its rotmat + anchor row ----
    if (lane == mi) {
        float P00 = A0*R00 + A1*R10 + A2*R20;
        float P01 = A0*R01 + A1*R11 + A2*R21;
        float P02 = A0*R02 + A1*R12 + A2*R22;
        float P10 = A3*R00 + A4*R10 + A5*R20;
        float P11 = A3*R01 + A4*R11 + A5*R21;
        float P12 = A3*R02 + A4*R12 + A5*R22;
        float P20 = A6*R00 + A7*R10 + A8*R20;
        float P21 = A6*R01 + A7*R11 + A8*R21;
        float P22 = A6*R02 + A7*R12 + A8*R22;
        const float* tR = sg + wave * WPAD + 29 * 9;   // true_R from LDS
        float tr = P00*tR[0] + P01*tR[1] + P02*tR[2]
                 + P10*tR[3] + P11*tR[4] + P12*tR[5]
                 + P20*tR[6] + P21*tR[7] + P22*tR[8];
        float cx = 0.5f * (tr - 1.0f);
        cx = fminf(fmaxf(cx, -1.0f + 1e-7f), 1.0f - 1e-7f);
        out[4 + b] = acosf(cx);
    }

    // ---- per-wave l2 butterfly; partials straight to global ----
    for (int off = 32; off; off >>= 1) acc += __shfl_xor(acc, off, 64);
    if (lane == 0) {
        l2p[b] = acc;
        lpp[b] = wlab - lse;
        crp[b] = (mi == lab) ? 1.0f : 0.0f;
    }
}

// ---------------------------------------------------------------------------
// Finalize: 1024 threads, float4 strided loads, per-thread double accumulation,
// deterministic shfl+LDS tree.
// ---------------------------------------------------------------------------
__global__ __launch_bounds__(1024) void mtl_final(
    const float* __restrict__ l2p,
    const float* __restrict__ lpp,
    const float* __restrict__ crp,
    float*       __restrict__ out)
{
    const int tid  = threadIdx.x;
    const int lane = tid & 63;
    const int wave = tid >> 6;

    double l2 = 0.0, lp = 0.0, cr = 0.0;
    const float4* l2p4 = (const float4*)l2p;   // 32768/4 = 8192
    const float4* lpp4 = (const float4*)lpp;
    const float4* crp4 = (const float4*)crp;
    for (int i = tid; i < Bc / 4; i += 1024) {
        float4 v = l2p4[i];
        l2 += (double)v.x + (double)v.y + (double)v.z + (double)v.w;
        float4 u = lpp4[i];
        lp += (double)u.x + (double)u.y + (double)u.z + (double)u.w;
        float4 c = crp4[i];
        cr += (double)c.x + (double)c.y + (double)c.z + (double)c.w;
    }

    for (int off = 32; off; off >>= 1) {
        l2 += __shfl_xor(l2, off, 64);
        lp += __shfl_xor(lp, off, 64);
        cr += __shfl_xor(cr, off, 64);
    }
    __shared__ double s_l2[16], s_lp[16], s_cr[16];
    if (lane == 0) { s_l2[wave] = l2; s_lp[wave] = lp; s_cr[wave] = cr; }
    __syncthreads();
    if (tid == 0) {
        double t2 = 0.0, tp = 0.0, tc = 0.0;
        for (int i = 0; i < 16; ++i) { t2 += s_l2[i]; tp += s_lp[i]; tc += s_cr[i]; }
        float cls = (float)(-tp / (double)Bc);
        float l2s = (float)(10.0 * t2);      // W_LOSS * l2_loss
        out[0] = cls + l2s;                  // loss
        out[1] = cls;                        // cls_loss
        out[2] = l2s;                        // W_LOSS * l2_loss
        out[3] = (float)(tc / (double)Bc);   // r_acc
    }
}

extern "C" void kernel_launch(void* const* d_in, const int* in_sizes, int n_in,
                              void* d_out, int out_size, void* d_ws, size_t ws_size,
                              hipStream_t stream) {
    const float* wts     = (const float*)d_in[0];
    const int*   label   = (const int*)d_in[1];
    const float* y       = (const float*)d_in[2];
    const float* gt_R    = (const float*)d_in[3];
    const float* anchors = (const float*)d_in[4];
    float* out = (float*)d_out;

    float* l2p = (float*)d_ws;       // Bc floats
    float* lpp = l2p + Bc;           // Bc floats
    float* crp = lpp + Bc;           // Bc floats  (384 KB total)

    mtl_all  <<<NBLK, 256, 0, stream>>>(wts, label, y, gt_R, anchors,
                                        out, l2p, lpp, crp);
    mtl_final<<<1, 1024, 0, stream>>>(l2p, lpp, crp, out);
}